// Round 1
// 368.852 us; speedup vs baseline: 1.0537x; 1.0537x over previous
//
#include <hip/hip_runtime.h>
#include <math.h>

#define B_ 32
#define S_ 2048
#define H_ 1024
#define U_ 128

// workspace layout (float offsets, all 16B-aligned)
#define OFF_VPART 0u          // 8*32*1024    = 262144
#define OFF_V     262144u     // 32*1024      = 32768
#define OFF_PM    294912u     // 32*32        = 1024
#define OFF_PL    295936u     // 32*32        = 1024
#define OFF_PCTX  296960u     // 32*32*1024   = 1048576
#define OFF_DPART 1345536u    // 8*32*128     = 32768
// total ~5.5 MB

typedef float vfloat4 __attribute__((ext_vector_type(4)));

static __device__ __forceinline__ float4 ntload4(const float* p) {
    vfloat4 v = __builtin_nontemporal_load((const vfloat4*)p);
    return make_float4(v.x, v.y, v.z, v.w);
}

// ---------------------------------------------------------------------------
// Kernel A: v_part[kc][b][h] = sum over k-chunk of W[h,k] * h_t[b,k]
// grid (16, 8): h-chunks of 64, k-chunks of 128. 256 threads.
__global__ __launch_bounds__(256) void k_vpart(const float* __restrict__ hid,
                                               const float* __restrict__ W,
                                               float* __restrict__ ws) {
    __shared__ float ht[32][128];   // h_t slice for all 32 batches, 16 KB
    const int t  = threadIdx.x;
    const int h0 = blockIdx.x * 64;
    const int k0 = blockIdx.y * 128;
    #pragma unroll
    for (int i = 0; i < 4; ++i) {
        int f4 = i * 256 + t;            // 0..1023
        int bl = f4 >> 5;                // batch
        int k4 = f4 & 31;                // float4 within row
        float4 src = *(const float4*)(hid + ((size_t)bl * S_ + (S_ - 1)) * H_ + k0 + k4 * 4);
        *(float4*)&ht[bl][k4 * 4] = src;
    }
    __syncthreads();
    const int hl = t & 63;               // h within chunk
    const int g  = t >> 6;               // batch group (8 batches each)
    const int h  = h0 + hl;
    float acc[8];
    #pragma unroll
    for (int i = 0; i < 8; ++i) acc[i] = 0.f;
    const float4* Wr = (const float4*)(W + (size_t)h * H_ + k0);
    for (int k4 = 0; k4 < 32; ++k4) {
        float4 w4 = Wr[k4];
        float wv[4] = {w4.x, w4.y, w4.z, w4.w};
        #pragma unroll
        for (int c = 0; c < 4; ++c) {
            float w = wv[c];
            int kk = k4 * 4 + c;
            #pragma unroll
            for (int bb = 0; bb < 8; ++bb)
                acc[bb] += w * ht[g * 8 + bb][kk];
        }
    }
    float* vpart = ws + OFF_VPART;
    const int kc = blockIdx.y;
    #pragma unroll
    for (int bb = 0; bb < 8; ++bb)
        vpart[((size_t)kc * 32 + (g * 8 + bb)) * H_ + h] = acc[bb];
}

// Kernel A2: v[b][h] = sum_kc v_part[kc][b][h]
__global__ __launch_bounds__(256) void k_vreduce(float* __restrict__ ws) {
    int e = blockIdx.x * 256 + threadIdx.x;   // < 32768
    const float* vp = ws + OFF_VPART;
    float s = 0.f;
    #pragma unroll
    for (int kc = 0; kc < 8; ++kc) s += vp[kc * 32768 + e];
    ws[OFF_V + e] = s;
}

// ---------------------------------------------------------------------------
// Kernel B: fused score + online softmax + context partial, flash-style.
// One wave owns 16 consecutive s-rows, 2 rows/iter for ILP (8 float4 in flight).
// grid 1024 blocks x 256 threads = 4096 waves. 4 blocks/CU resident.
// NEW: the 4 waves of a block merge their partials in LDS (exact softmax merge),
// so only 32 partials/batch hit the workspace (pctx 16 MB -> 4 MB).
__global__ __launch_bounds__(256) void k_flash(const float* __restrict__ hid,
                                               float* __restrict__ ws) {
    __shared__ float sm[4], sl[4];
    __shared__ __align__(16) float sc[4][1024];   // 16 KB
    const int t    = threadIdx.x;
    const int lane = t & 63;
    const int wave = t >> 6;
    const int b    = blockIdx.x >> 5;
    const int blk  = blockIdx.x & 31;
    const int wi   = blk * 4 + wave;   // 0..127 within batch
    const int s0   = wi * 16;

    const float* vrow = ws + OFF_V + (size_t)b * H_;
    float4 v4[4], c4[4];
    #pragma unroll
    for (int j = 0; j < 4; ++j) {
        v4[j] = *(const float4*)(vrow + j * 256 + lane * 4);
        c4[j] = make_float4(0.f, 0.f, 0.f, 0.f);
    }
    float m = -INFINITY, l = 0.f;
    const float* base = hid + ((size_t)b * S_ + s0) * H_ + lane * 4;

    for (int r = 0; r < 16; r += 2) {
        const float* r0 = base + (size_t)r * H_;
        const float* r1 = r0 + H_;
        float4 a4[4], b4[4];
        #pragma unroll
        for (int j = 0; j < 4; ++j) a4[j] = ntload4(r0 + j * 256);
        #pragma unroll
        for (int j = 0; j < 4; ++j) b4[j] = ntload4(r1 + j * 256);
        float p0 = 0.f, p1 = 0.f;
        #pragma unroll
        for (int j = 0; j < 4; ++j) {
            p0 += a4[j].x * v4[j].x + a4[j].y * v4[j].y + a4[j].z * v4[j].z + a4[j].w * v4[j].w;
            p1 += b4[j].x * v4[j].x + b4[j].y * v4[j].y + b4[j].z * v4[j].z + b4[j].w * v4[j].w;
        }
        #pragma unroll
        for (int off = 32; off > 0; off >>= 1) {
            p0 += __shfl_xor(p0, off, 64);
            p1 += __shfl_xor(p1, off, 64);
        }
        float pmax = fmaxf(p0, p1);
        if (pmax > m) {                    // wave-uniform branch
            float alpha = __expf(m - pmax);   // first iter: exp(-inf)=0
            l *= alpha;
            #pragma unroll
            for (int j = 0; j < 4; ++j) {
                c4[j].x *= alpha; c4[j].y *= alpha; c4[j].z *= alpha; c4[j].w *= alpha;
            }
            m = pmax;
        }
        float e0 = __expf(p0 - m), e1 = __expf(p1 - m);
        l += e0 + e1;
        #pragma unroll
        for (int j = 0; j < 4; ++j) {
            c4[j].x += e0 * a4[j].x + e1 * b4[j].x;
            c4[j].y += e0 * a4[j].y + e1 * b4[j].y;
            c4[j].z += e0 * a4[j].z + e1 * b4[j].z;
            c4[j].w += e0 * a4[j].w + e1 * b4[j].w;
        }
    }

    // ---- in-block merge of the 4 wave partials (exact) ----
    if (lane == 0) { sm[wave] = m; sl[wave] = l; }
    #pragma unroll
    for (int j = 0; j < 4; ++j)
        *(float4*)&sc[wave][j * 256 + lane * 4] = c4[j];
    __syncthreads();

    float M = fmaxf(fmaxf(sm[0], sm[1]), fmaxf(sm[2], sm[3]));
    const int col = t * 4;               // 256 threads x 4 cols = 1024
    float4 acc = make_float4(0.f, 0.f, 0.f, 0.f);
    float Lm = 0.f;
    #pragma unroll
    for (int w = 0; w < 4; ++w) {
        float wt = __expf(sm[w] - M);
        float4 cw = *(const float4*)&sc[w][col];
        acc.x += wt * cw.x; acc.y += wt * cw.y;
        acc.z += wt * cw.z; acc.w += wt * cw.w;
        Lm += wt * sl[w];
    }
    const int pid = b * 32 + blk;        // 32 partials per batch now
    *(float4*)(ws + OFF_PCTX + (size_t)pid * H_ + col) = acc;
    if (t == 0) { ws[OFF_PM + pid] = M; ws[OFF_PL + pid] = Lm; }
}

// ---------------------------------------------------------------------------
// Kernel D1: partial output GEMM with the global softmax merge fused in.
// pre=[ctx, h_t] (2048) @ W2 (2048x128), split into 8 j-chunks of 256.
// Blocks jc<4 build their 256-col slice of ctx directly from the 32 partials.
// grid (8 j-chunks, 32 batches) x 128 threads (one per unit).
__global__ __launch_bounds__(128) void k_out_part(const float* __restrict__ hid,
                                                  const float* __restrict__ W2,
                                                  float* __restrict__ ws) {
    __shared__ float pre[256];
    const int jc = blockIdx.x;
    const int b  = blockIdx.y;
    const int t  = threadIdx.x;
    if (jc < 4) {
        const float* pm = ws + OFF_PM + b * 32;
        const float* pl = ws + OFF_PL + b * 32;
        float M = -INFINITY;
        #pragma unroll
        for (int i = 0; i < 32; ++i) M = fmaxf(M, pm[i]);
        float w[32];                       // fully unrolled -> stays in VGPRs
        float L = 0.f;
        #pragma unroll
        for (int i = 0; i < 32; ++i) { w[i] = __expf(pm[i] - M); L += w[i] * pl[i]; }
        float2 acc = make_float2(0.f, 0.f);
        const float* basep = ws + OFF_PCTX + (size_t)b * 32 * H_ + jc * 256 + t * 2;
        #pragma unroll
        for (int i = 0; i < 32; ++i) {
            float2 cv = *(const float2*)(basep + (size_t)i * H_);
            acc.x += w[i] * cv.x; acc.y += w[i] * cv.y;
        }
        float invL = 1.f / L;
        pre[t * 2]     = acc.x * invL;
        pre[t * 2 + 1] = acc.y * invL;
    } else {
        const float* hrow = hid + ((size_t)b * S_ + (S_ - 1)) * H_ + (jc - 4) * 256;
        float2 h2 = *(const float2*)(hrow + t * 2);
        pre[t * 2]     = h2.x;
        pre[t * 2 + 1] = h2.y;
    }
    __syncthreads();
    float acc = 0.f;
    const float* w2 = W2 + (size_t)jc * 256 * U_ + t;
    #pragma unroll 8
    for (int jj = 0; jj < 256; ++jj)
        acc += pre[jj] * w2[(size_t)jj * U_];
    ws[OFF_DPART + ((size_t)jc * 32 + b) * U_ + t] = acc;
}

// Kernel D2: reduce J-chunks + tanh.
__global__ __launch_bounds__(256) void k_out_final(const float* __restrict__ ws,
                                                   float* __restrict__ out) {
    int idx = blockIdx.x * 256 + threadIdx.x;    // < 4096
    float s = 0.f;
    #pragma unroll
    for (int jc = 0; jc < 8; ++jc) s += ws[OFF_DPART + jc * 4096 + idx];
    out[idx] = tanhf(s);
}

// ---------------------------------------------------------------------------
extern "C" void kernel_launch(void* const* d_in, const int* in_sizes, int n_in,
                              void* d_out, int out_size, void* d_ws, size_t ws_size,
                              hipStream_t stream) {
    const float* hid = (const float*)d_in[0];   // (32, 2048, 1024) fp32
    const float* W   = (const float*)d_in[1];   // (1024, 1024) fp32
    const float* W2  = (const float*)d_in[2];   // (2048, 128) fp32
    float* ws  = (float*)d_ws;
    float* out = (float*)d_out;                 // (32, 128) fp32

    hipLaunchKernelGGL(k_vpart,     dim3(16, 8), dim3(256), 0, stream, hid, W, ws);
    hipLaunchKernelGGL(k_vreduce,   dim3(128),   dim3(256), 0, stream, ws);
    hipLaunchKernelGGL(k_flash,     dim3(1024),  dim3(256), 0, stream, hid, ws);
    hipLaunchKernelGGL(k_out_part,  dim3(8, 32), dim3(128), 0, stream, hid, W2, ws);
    hipLaunchKernelGGL(k_out_final, dim3(16),    dim3(256), 0, stream, ws, out);
}